// Round 16
// baseline (299.057 us; speedup 1.0000x reference)
//
#include <hip/hip_runtime.h>
#include <math.h>

// LSTMClassifier fused kernel for MI355X (gfx950) — round 15
// 768 threads = 12 waves (3/SIMD): 8 SCAN waves (2/SIMD) + 4 GEMM waves.
//   scan wave w (0..7): gate-pair mapping — tileA = gates i|f, tileB = g|o
//     of units 8w..8w+7; 8 MFMA/step; gates reassembled with shfl_xor(8);
//     cell on lanes c<8 (32 cells/wave). Two scan waves per SIMD interleave
//     so ds_read/MFMA/exp latency hides under the other's issue stream.
//   gemm wave q (8..11): next chunk's xg = x·W_ih^T + bias, one M-tile
//     quarter per step (4 MFMA), stage x(ch+2) (issue t0, commit t6-12).
// Raw lgkmcnt barrier per step (global loads stay in flight).
// fp16 2-term weights (hi + lo*2^11), fp16 h, f32 xg (proven absmax ~1e-3).
// grid=256 (1 block/CU), 4 batch/block, LDS ~155 KB.

#define S_LEN  512
#define I_DIM  50
#define H_DIM  64
#define BB     4
#define TC     16
#define NCH    (S_LEN / TC)
#define KROW   40
#define XROW   72
#define XSHALF (BB * TC * XROW)      // 4608 halfwords per Xs buffer
#define NXE    (BB * TC * I_DIM)     // 3200 x elems per chunk
#define F1_DIM 32
#define C_DIM  2
#define ILO    (1.0f / 2048.0f)

typedef __attribute__((ext_vector_type(8))) _Float16 f16x8;
typedef __attribute__((ext_vector_type(4))) float    f32x4;

__device__ __forceinline__ float fast_rcp(float x) { return __builtin_amdgcn_rcpf(x); }
__device__ __forceinline__ float sigm(float v) { return fast_rcp(1.0f + __expf(-v)); }
__device__ __forceinline__ float tanh_fast(float v) {
    return 1.0f - 2.0f * fast_rcp(__expf(2.0f * v) + 1.0f);
}

// Weight fragment pair: hi = fp16(w), lo = fp16((w-hi)*2048).
// ktg 0,1 -> W_ih (k<50 else 0); ktg 2,3 -> W_hh (k-64).
__device__ __forceinline__ void load_wfrag(const float* __restrict__ Wih,
                                           const float* __restrict__ Whh,
                                           int ktg, int row, int hk,
                                           f16x8& bh, f16x8& bl) {
    #pragma unroll
    for (int j = 0; j < 8; ++j) {
        const int kk = ktg * 32 + hk * 8 + j;
        float wv;
        if (ktg < 2) wv = (kk < I_DIM) ? Wih[row * I_DIM + kk] : 0.0f;
        else         wv = Whh[row * H_DIM + (kk - 64)];
        const _Float16 h = (_Float16)wv;
        bh[j] = h;
        bl[j] = (_Float16)((wv - (float)h) * 2048.0f);
    }
}

#define MFMA16(A, B, C) __builtin_amdgcn_mfma_f32_16x16x32_f16(A, B, C, 0, 0, 0)

// raw barrier: order LDS only; leave global loads in flight
#define BAR() do { asm volatile("s_waitcnt lgkmcnt(0)" ::: "memory"); \
                   __builtin_amdgcn_s_barrier(); } while (0)

__global__ __launch_bounds__(768, 3)
void lstm_mfma(const float* __restrict__ x,
               const float* __restrict__ W_ih, const float* __restrict__ W_hh,
               const float* __restrict__ b_ih, const float* __restrict__ b_hh,
               const float* __restrict__ W1,  const float* __restrict__ b1,
               const float* __restrict__ W2,  const float* __restrict__ b2,
               float* __restrict__ out)
{
    __shared__ __align__(16) _Float16 Hst[2][2][16][KROW];        //  5 KB
    __shared__ __align__(16) _Float16 Xs[2][BB * TC][XROW];       // 18 KB
    __shared__ __align__(16) float    XGb[2][TC][BB][H_DIM][4];   // 128 KB
    __shared__ float f1buf[BB][F1_DIM];

    const int u  = threadIdx.x;      // 0..767
    const int w  = u >> 6;           // wave 0..11
    const int l  = u & 63;
    const int c  = l & 15;
    const int hk = l >> 4;
    const int b0 = blockIdx.x * BB;
    const bool is_scan = (w < 8);
    const int q  = w & 3;            // gemm role-local wave id
    const f32x4 Z4 = {0.f, 0.f, 0.f, 0.f};

    // scan mapping: unit un = 8w + (c&7); gate-half gh = c>>3
    const int un = 8 * (w & 7) + (c & 7);
    const int gh = c >> 3;

    // ---- role fragments ----
    f16x8 sA0h, sA0l, sA1h, sA1l, sB0h, sB0l, sB1h, sB1l;        // scan: W_hh
    f16x8 g00h, g00l, g01h, g01l, g10h, g10l, g11h, g11l,
          g20h, g20l, g21h, g21l, g30h, g30l, g31h, g31l;        // gemm: W_ih
    float bs0 = 0.f, bs1 = 0.f, bs2 = 0.f, bs3 = 0.f;
    float cst = 0.0f;                // scan: cell state (batch hk, unit un), c<8

    // gemm persistent tile state
    f16x8 ga0, ga1;
    f32x4 G0, H0, G1, H1, G2, H2, G3, H3;

    // gemm staging descriptors (13 slots x 256 threads >= 3200)
    const float *xp0=x,*xp1=x,*xp2=x,*xp3=x,*xp4=x,*xp5=x,*xp6=x,
                *xp7=x,*xp8=x,*xp9=x,*xp10=x,*xp11=x,*xp12=x;
    int  ld0=0,ld1=0,ld2=0,ld3=0,ld4=0,ld5=0,ld6=0,ld7=0,ld8=0,ld9=0,ld10=0,ld11=0,ld12=0;
    bool v0_=false,v1_=false,v2_=false,v3_=false,v4_=false,v5_=false,v6_=false,
         v7_=false,v8_=false,v9_=false,v10_=false,v11_=false,v12_=false;

    if (is_scan) {
        // tileA: gate gh (i/f), tileB: gate gh+2 (g/o), unit un
        load_wfrag(W_ih, W_hh, 2, gh * H_DIM + un,       hk, sA0h, sA0l);
        load_wfrag(W_ih, W_hh, 3, gh * H_DIM + un,       hk, sA1h, sA1l);
        load_wfrag(W_ih, W_hh, 2, (gh + 2) * H_DIM + un, hk, sB0h, sB0l);
        load_wfrag(W_ih, W_hh, 3, (gh + 2) * H_DIM + un, hk, sB1h, sB1l);
    } else {
        const int base = 16 * q + c;
        load_wfrag(W_ih, W_hh, 0, 0 * H_DIM + base, hk, g00h, g00l);
        load_wfrag(W_ih, W_hh, 1, 0 * H_DIM + base, hk, g01h, g01l);
        load_wfrag(W_ih, W_hh, 0, 1 * H_DIM + base, hk, g10h, g10l);
        load_wfrag(W_ih, W_hh, 1, 1 * H_DIM + base, hk, g11h, g11l);
        load_wfrag(W_ih, W_hh, 0, 2 * H_DIM + base, hk, g20h, g20l);
        load_wfrag(W_ih, W_hh, 1, 2 * H_DIM + base, hk, g21h, g21l);
        load_wfrag(W_ih, W_hh, 0, 3 * H_DIM + base, hk, g30h, g30l);
        load_wfrag(W_ih, W_hh, 1, 3 * H_DIM + base, hk, g31h, g31l);
        bs0 = b_ih[0 * H_DIM + base] + b_hh[0 * H_DIM + base];
        bs1 = b_ih[1 * H_DIM + base] + b_hh[1 * H_DIM + base];
        bs2 = b_ih[2 * H_DIM + base] + b_hh[2 * H_DIM + base];
        bs3 = b_ih[3 * H_DIM + base] + b_hh[3 * H_DIM + base];

        const int ug = u - 512;      // 0..255
#define PRE(E) { const int idx = ug + (E) * 256; if (idx < NXE) { \
            const int bb_ = idx / (TC * I_DIM); \
            const int rm_ = idx - bb_ * (TC * I_DIM); \
            const int t_  = rm_ / I_DIM; \
            const int ii_ = rm_ - t_ * I_DIM; \
            xp##E = x + (size_t)(b0 + bb_) * (S_LEN * I_DIM) + t_ * I_DIM + ii_; \
            ld##E = (bb_ * TC + t_) * XROW + ii_; v##E##_ = true; } }
        PRE(0) PRE(1) PRE(2) PRE(3) PRE(4) PRE(5) PRE(6)
        PRE(7) PRE(8) PRE(9) PRE(10) PRE(11) PRE(12)
#undef PRE
    }

    // ---- zero Hst (h0) and Xs (k-pad) ----
    for (int i = u; i < 1280; i += 768) ((unsigned*)Hst)[i] = 0u;
    for (int i = u; i < 4608; i += 768) ((unsigned*)Xs)[i]  = 0u;
    __syncthreads();

    // ---- prologue: stage x(ch0)->Xs[0], x(ch1)->Xs[1] ----
    if (!is_scan) {
#define STG(E, CH, BUF) if (v##E##_) { \
        const float t_ = xp##E[(size_t)(CH) * (TC * I_DIM)]; \
        *((_Float16*)Xs + (BUF) * XSHALF + ld##E) = (_Float16)t_; }
        STG(0,0,0) STG(1,0,0) STG(2,0,0) STG(3,0,0) STG(4,0,0) STG(5,0,0)
        STG(6,0,0) STG(7,0,0) STG(8,0,0) STG(9,0,0) STG(10,0,0) STG(11,0,0) STG(12,0,0)
        STG(0,1,1) STG(1,1,1) STG(2,1,1) STG(3,1,1) STG(4,1,1) STG(5,1,1)
        STG(6,1,1) STG(7,1,1) STG(8,1,1) STG(9,1,1) STG(10,1,1) STG(11,1,1) STG(12,1,1)
#undef STG
    }
    __syncthreads();

#define GPK(DB, MT, I) { f32x4 pk; \
    pk[0] = G0[I] + fmaf(ILO, H0[I], bs0); \
    pk[1] = G1[I] + fmaf(ILO, H1[I], bs1); \
    pk[2] = G2[I] + fmaf(ILO, H2[I], bs2); \
    pk[3] = G3[I] + fmaf(ILO, H3[I], bs3); \
    *(f32x4*)&XGb[DB][4 * hk + (I)][MT][16 * q + c][0] = pk; }

#define GQ0(SB, MT) { \
    ga0 = *(const f16x8*)&Xs[SB][(MT) * 16 + c][hk * 8]; \
    ga1 = *(const f16x8*)&Xs[SB][(MT) * 16 + c][32 + hk * 8]; \
    G0 = MFMA16(ga0, g00h, Z4); G0 = MFMA16(ga1, g01h, G0); \
    H0 = MFMA16(ga0, g00l, Z4); H0 = MFMA16(ga1, g01l, H0); }
#define GQ1() { \
    G1 = MFMA16(ga0, g10h, Z4); G1 = MFMA16(ga1, g11h, G1); \
    H1 = MFMA16(ga0, g10l, Z4); H1 = MFMA16(ga1, g11l, H1); }
#define GQ2() { \
    G2 = MFMA16(ga0, g20h, Z4); G2 = MFMA16(ga1, g21h, G2); \
    H2 = MFMA16(ga0, g20l, Z4); H2 = MFMA16(ga1, g21l, H2); }
#define GQ3(DB, MT) { \
    G3 = MFMA16(ga0, g30h, Z4); G3 = MFMA16(ga1, g31h, G3); \
    H3 = MFMA16(ga0, g30l, Z4); H3 = MFMA16(ga1, g31l, H3); \
    GPK(DB, MT, 0) GPK(DB, MT, 1) GPK(DB, MT, 2) GPK(DB, MT, 3) }

    // prologue: XG[0] from Xs[0] (full, one-time)
    if (!is_scan) {
        GQ0(0, 0) GQ1() GQ2() GQ3(0, 0)
        GQ0(0, 1) GQ1() GQ2() GQ3(0, 1)
        GQ0(0, 2) GQ1() GQ2() GQ3(0, 2)
        GQ0(0, 3) GQ1() GQ2() GQ3(0, 3)
    }
    __syncthreads();

#define SCAN_STEP(TT, CUR) { \
    const int p = (TT) & 1; \
    const f16x8 ah0 = *(const f16x8*)&Hst[p][0][c][hk * 8]; \
    const f16x8 ah1 = *(const f16x8*)&Hst[p][1][c][hk * 8]; \
    const float xgA = XGb[CUR][TT][hk][un][gh]; \
    const float xgB = XGb[CUR][TT][hk][un][gh + 2]; \
    __builtin_amdgcn_s_setprio(1); \
    f32x4 A0 = MFMA16(ah0, sA0h, Z4); A0 = MFMA16(ah1, sA1h, A0); \
    f32x4 L0 = MFMA16(ah0, sA0l, Z4); L0 = MFMA16(ah1, sA1l, L0); \
    f32x4 B0 = MFMA16(ah0, sB0h, Z4); B0 = MFMA16(ah1, sB1h, B0); \
    f32x4 L1 = MFMA16(ah0, sB0l, Z4); L1 = MFMA16(ah1, sB1l, L1); \
    __builtin_amdgcn_s_setprio(0); \
    const float v0 = A0[0] + fmaf(ILO, L0[0], xgA);   /* i (c<8) / f (c>=8) */ \
    const float v1 = B0[0] + fmaf(ILO, L1[0], xgB);   /* g (c<8) / o (c>=8) */ \
    const float y0 = __shfl_xor(v0, 8); \
    const float y1 = __shfl_xor(v1, 8); \
    if (c < 8) { \
        const float gi = sigm(v0), gf = sigm(y0); \
        const float gg = tanh_fast(v1), go = sigm(y1); \
        cst = fmaf(gf, cst, gi * gg); \
        const float hv = go * tanh_fast(cst); \
        Hst[p ^ 1][un >> 5][4 * hk][un & 31] = (_Float16)hv; \
    } }

#define XISS(E, CH2) if (v##E##_) xr##E = xp##E[(size_t)(CH2) * (TC * I_DIM)];
#define XCMT(E, BUF) if (v##E##_) *((_Float16*)Xs + (BUF) * XSHALF + ld##E) = (_Float16)xr##E;

    // ---- main loop: scan chunk ch; gemm builds chunk ch+1 (quarter/step) ----
    for (int ch = 0; ch < NCH; ++ch) {
        const int cur = ch & 1, nx = cur ^ 1;
        const bool cmp = (ch + 1 < NCH);
        const bool stg = (ch + 2 < NCH);
        float xr0=0,xr1=0,xr2=0,xr3=0,xr4=0,xr5=0,xr6=0,
              xr7=0,xr8=0,xr9=0,xr10=0,xr11=0,xr12=0;

        #pragma unroll
        for (int tt = 0; tt < TC; ++tt) {
            if (is_scan) {
                SCAN_STEP(tt, cur)
            } else {
                if (cmp) {
                    const int mt = tt >> 2, gq = tt & 3;
                    if (gq == 0) { GQ0(nx, mt) }
                    if (gq == 1) { GQ1() }
                    if (gq == 2) { GQ2() }
                    if (gq == 3) { GQ3(nx, mt) }
                }
                if (stg) {
                    if (tt == 0) {
                        XISS(0, ch+2) XISS(1, ch+2) XISS(2, ch+2) XISS(3, ch+2)
                        XISS(4, ch+2) XISS(5, ch+2) XISS(6, ch+2) XISS(7, ch+2)
                        XISS(8, ch+2) XISS(9, ch+2) XISS(10, ch+2) XISS(11, ch+2)
                        XISS(12, ch+2)
                    }
                    if (tt == 6)  { XCMT(0, cur)  XCMT(1, cur) }
                    if (tt == 7)  { XCMT(2, cur)  XCMT(3, cur) }
                    if (tt == 8)  { XCMT(4, cur)  XCMT(5, cur) }
                    if (tt == 9)  { XCMT(6, cur)  XCMT(7, cur) }
                    if (tt == 10) { XCMT(8, cur)  XCMT(9, cur) }
                    if (tt == 11) { XCMT(10, cur) XCMT(11, cur) }
                    if (tt == 12) { XCMT(12, cur) }
                }
            }
            BAR();
        }
    }
#undef SCAN_STEP
#undef GQ0
#undef GQ1
#undef GQ2
#undef GQ3
#undef GPK
#undef XISS
#undef XCMT

    __syncthreads();

    // ---- classifier head; h_last (fp16) in Hst[0], rows 4b ----
    if (u < BB * F1_DIM) {           // 128 threads
        const int b = u >> 5, f = u & 31;
        float acc = b1[f];
        #pragma unroll
        for (int j = 0; j < H_DIM; ++j) {
            const float hj = (float)Hst[0][j >> 5][4 * b][j & 31];
            acc = fmaf(hj, W1[f * H_DIM + j], acc);
        }
        f1buf[b][f] = fmaxf(acc, 0.0f);
    }
    __syncthreads();
    if (u < BB * C_DIM) {            // 8 threads
        const int b = u >> 1, cl = u & 1;
        float acc = b2[cl];
        #pragma unroll
        for (int f = 0; f < F1_DIM; ++f)
            acc = fmaf(f1buf[b][f], W2[cl * F1_DIM + f], acc);
        out[(size_t)(b0 + b) * C_DIM + cl] = acc;
    }
}

extern "C" void kernel_launch(void* const* d_in, const int* in_sizes, int n_in,
                              void* d_out, int out_size, void* d_ws, size_t ws_size,
                              hipStream_t stream) {
    const float* x   = (const float*)d_in[0];
    const float* Wih = (const float*)d_in[1];
    const float* Whh = (const float*)d_in[2];
    const float* bih = (const float*)d_in[3];
    const float* bhh = (const float*)d_in[4];
    const float* W1  = (const float*)d_in[5];
    const float* b1  = (const float*)d_in[6];
    const float* W2  = (const float*)d_in[7];
    const float* b2  = (const float*)d_in[8];
    float* out = (float*)d_out;

    hipLaunchKernelGGL(lstm_mfma, dim3(256), dim3(768), 0, stream,
                       x, Wih, Whh, bih, bhh, W1, b1, W2, b2, out);
}

// Round 17
// 190.197 us; speedup vs baseline: 1.5724x; 1.5724x over previous
//
#include <hip/hip_runtime.h>
#include <math.h>

// LSTMClassifier fused kernel for MI355X (gfx950) — round 16
// r14 structure (best: 204 µs) with a shorter scan critical path:
//   - recurrent W_hh weights SINGLE fp16 (hi only): 8 MFMA/wave/step,
//     no ILO combine in the serial chain (error budget ~1-3e-4, OK).
//   - xg folded into the MFMA C-input: gate value = A[0] of the last MFMA.
//   - x-GEMM keeps fp16 2-term (hi + lo*2^11) for the bias+input base.
//   waves 0-3 (scan): h·W_hh, 4 gate-tiles/wave, gates lane-local, cell on
//     all 64 lanes, raw lgkmcnt barrier per step.
//   waves 4-7 (gemm): next chunk's xg quarter-per-step + x staging
//     (global loads stay in flight across raw barriers).
// 512 threads, __launch_bounds__(512,1) (NO register cap -> no spills),
// grid=256 (1 block/CU), 4 batch/block, LDS ~155 KB.

#define S_LEN  512
#define I_DIM  50
#define H_DIM  64
#define BB     4
#define TC     16
#define NCH    (S_LEN / TC)
#define KROW   40
#define XROW   72
#define XSHALF (BB * TC * XROW)      // 4608 halfwords per Xs buffer
#define NXE    (BB * TC * I_DIM)     // 3200 x elems per chunk
#define F1_DIM 32
#define C_DIM  2
#define ILO    (1.0f / 2048.0f)

typedef __attribute__((ext_vector_type(8))) _Float16 f16x8;
typedef __attribute__((ext_vector_type(4))) float    f32x4;

__device__ __forceinline__ float fast_rcp(float x) { return __builtin_amdgcn_rcpf(x); }
__device__ __forceinline__ float sigm(float v) { return fast_rcp(1.0f + __expf(-v)); }
__device__ __forceinline__ float tanh_fast(float v) {
    return 1.0f - 2.0f * fast_rcp(__expf(2.0f * v) + 1.0f);
}

// Weight fragment pair: hi = fp16(w), lo = fp16((w-hi)*2048).
// ktg 0,1 -> W_ih (k<50 else 0); ktg 2,3 -> W_hh (k-64).
__device__ __forceinline__ void load_wfrag(const float* __restrict__ Wih,
                                           const float* __restrict__ Whh,
                                           int ktg, int row, int hk,
                                           f16x8& bh, f16x8& bl) {
    #pragma unroll
    for (int j = 0; j < 8; ++j) {
        const int kk = ktg * 32 + hk * 8 + j;
        float wv;
        if (ktg < 2) wv = (kk < I_DIM) ? Wih[row * I_DIM + kk] : 0.0f;
        else         wv = Whh[row * H_DIM + (kk - 64)];
        const _Float16 h = (_Float16)wv;
        bh[j] = h;
        bl[j] = (_Float16)((wv - (float)h) * 2048.0f);
    }
}
// hi-only variant (scan W_hh)
__device__ __forceinline__ void load_wfrag_hi(const float* __restrict__ Whh,
                                              int ktg, int row, int hk, f16x8& bh) {
    #pragma unroll
    for (int j = 0; j < 8; ++j) {
        const int kk = ktg * 32 + hk * 8 + j;   // ktg 2,3
        bh[j] = (_Float16)Whh[row * H_DIM + (kk - 64)];
    }
}

#define MFMA16(A, B, C) __builtin_amdgcn_mfma_f32_16x16x32_f16(A, B, C, 0, 0, 0)

// raw barrier: order LDS only; leave global loads in flight
#define BAR() do { asm volatile("s_waitcnt lgkmcnt(0)" ::: "memory"); \
                   __builtin_amdgcn_s_barrier(); } while (0)

__global__ __launch_bounds__(512, 1)
void lstm_mfma(const float* __restrict__ x,
               const float* __restrict__ W_ih, const float* __restrict__ W_hh,
               const float* __restrict__ b_ih, const float* __restrict__ b_hh,
               const float* __restrict__ W1,  const float* __restrict__ b1,
               const float* __restrict__ W2,  const float* __restrict__ b2,
               float* __restrict__ out)
{
    __shared__ __align__(16) _Float16 Hst[2][2][16][KROW];        //  5 KB
    __shared__ __align__(16) _Float16 Xs[2][BB * TC][XROW];       // 18 KB
    __shared__ __align__(16) float    XGb[2][TC][BB][H_DIM][4];   // 128 KB
    __shared__ float f1buf[BB][F1_DIM];

    const int u  = threadIdx.x;      // 0..511
    const int w  = u >> 6;           // wave 0..7
    const int l  = u & 63;
    const int c  = l & 15;
    const int hk = l >> 4;
    const int b0 = blockIdx.x * BB;
    const bool is_scan = (w < 4);
    const int q  = w & 3;            // role-local wave id
    const f32x4 Z4 = {0.f, 0.f, 0.f, 0.f};

    // ---- role fragments ----
    f16x8 s00h, s01h, s10h, s11h, s20h, s21h, s30h, s31h;        // scan: W_hh hi
    f16x8 g00h, g00l, g01h, g01l, g10h, g10l, g11h, g11l,
          g20h, g20l, g21h, g21l, g30h, g30l, g31h, g31l;        // gemm: W_ih 2-term
    float bs0 = 0.f, bs1 = 0.f, bs2 = 0.f, bs3 = 0.f;
    float cst = 0.0f;                // scan: cell state (batch hk, unit 16w+c)

    // gemm persistent tile state
    f16x8 ga0, ga1;
    f32x4 G0, H0, G1, H1, G2, H2, G3, H3;

    // gemm staging descriptors (13 slots x 256 threads >= 3200)
    const float *xp0=x,*xp1=x,*xp2=x,*xp3=x,*xp4=x,*xp5=x,*xp6=x,
                *xp7=x,*xp8=x,*xp9=x,*xp10=x,*xp11=x,*xp12=x;
    int  ld0=0,ld1=0,ld2=0,ld3=0,ld4=0,ld5=0,ld6=0,ld7=0,ld8=0,ld9=0,ld10=0,ld11=0,ld12=0;
    bool v0=false,v1=false,v2=false,v3=false,v4=false,v5=false,v6=false,
         v7=false,v8=false,v9=false,v10=false,v11=false,v12=false;

    if (is_scan) {
        const int base = 16 * w + c;
        load_wfrag_hi(W_hh, 2, 0 * H_DIM + base, hk, s00h);
        load_wfrag_hi(W_hh, 3, 0 * H_DIM + base, hk, s01h);
        load_wfrag_hi(W_hh, 2, 1 * H_DIM + base, hk, s10h);
        load_wfrag_hi(W_hh, 3, 1 * H_DIM + base, hk, s11h);
        load_wfrag_hi(W_hh, 2, 2 * H_DIM + base, hk, s20h);
        load_wfrag_hi(W_hh, 3, 2 * H_DIM + base, hk, s21h);
        load_wfrag_hi(W_hh, 2, 3 * H_DIM + base, hk, s30h);
        load_wfrag_hi(W_hh, 3, 3 * H_DIM + base, hk, s31h);
    } else {
        const int base = 16 * q + c;
        load_wfrag(W_ih, W_hh, 0, 0 * H_DIM + base, hk, g00h, g00l);
        load_wfrag(W_ih, W_hh, 1, 0 * H_DIM + base, hk, g01h, g01l);
        load_wfrag(W_ih, W_hh, 0, 1 * H_DIM + base, hk, g10h, g10l);
        load_wfrag(W_ih, W_hh, 1, 1 * H_DIM + base, hk, g11h, g11l);
        load_wfrag(W_ih, W_hh, 0, 2 * H_DIM + base, hk, g20h, g20l);
        load_wfrag(W_ih, W_hh, 1, 2 * H_DIM + base, hk, g21h, g21l);
        load_wfrag(W_ih, W_hh, 0, 3 * H_DIM + base, hk, g30h, g30l);
        load_wfrag(W_ih, W_hh, 1, 3 * H_DIM + base, hk, g31h, g31l);
        bs0 = b_ih[0 * H_DIM + base] + b_hh[0 * H_DIM + base];
        bs1 = b_ih[1 * H_DIM + base] + b_hh[1 * H_DIM + base];
        bs2 = b_ih[2 * H_DIM + base] + b_hh[2 * H_DIM + base];
        bs3 = b_ih[3 * H_DIM + base] + b_hh[3 * H_DIM + base];

        const int ug = u - 256;      // 0..255
#define PRE(E) { const int idx = ug + (E) * 256; if (idx < NXE) { \
            const int bb_ = idx / (TC * I_DIM); \
            const int rm_ = idx - bb_ * (TC * I_DIM); \
            const int t_  = rm_ / I_DIM; \
            const int ii_ = rm_ - t_ * I_DIM; \
            xp##E = x + (size_t)(b0 + bb_) * (S_LEN * I_DIM) + t_ * I_DIM + ii_; \
            ld##E = (bb_ * TC + t_) * XROW + ii_; v##E = true; } }
        PRE(0) PRE(1) PRE(2) PRE(3) PRE(4) PRE(5) PRE(6)
        PRE(7) PRE(8) PRE(9) PRE(10) PRE(11) PRE(12)
#undef PRE
    }

    // ---- zero Hst (h0) and Xs (k-pad) ----
    for (int i = u; i < 1280; i += 512) ((unsigned*)Hst)[i] = 0u;
    for (int i = u; i < 4608; i += 512) ((unsigned*)Xs)[i]  = 0u;
    __syncthreads();

    // ---- prologue: stage x(ch0)->Xs[0], x(ch1)->Xs[1] ----
    if (!is_scan) {
#define STG(E, CH, BUF) if (v##E) { \
        const float t_ = xp##E[(size_t)(CH) * (TC * I_DIM)]; \
        *((_Float16*)Xs + (BUF) * XSHALF + ld##E) = (_Float16)t_; }
        STG(0,0,0) STG(1,0,0) STG(2,0,0) STG(3,0,0) STG(4,0,0) STG(5,0,0)
        STG(6,0,0) STG(7,0,0) STG(8,0,0) STG(9,0,0) STG(10,0,0) STG(11,0,0) STG(12,0,0)
        STG(0,1,1) STG(1,1,1) STG(2,1,1) STG(3,1,1) STG(4,1,1) STG(5,1,1)
        STG(6,1,1) STG(7,1,1) STG(8,1,1) STG(9,1,1) STG(10,1,1) STG(11,1,1) STG(12,1,1)
#undef STG
    }
    __syncthreads();

#define GPK(DB, MT, I) { f32x4 pk; \
    pk[0] = G0[I] + fmaf(ILO, H0[I], bs0); \
    pk[1] = G1[I] + fmaf(ILO, H1[I], bs1); \
    pk[2] = G2[I] + fmaf(ILO, H2[I], bs2); \
    pk[3] = G3[I] + fmaf(ILO, H3[I], bs3); \
    *(f32x4*)&XGb[DB][4 * hk + (I)][MT][16 * q + c][0] = pk; }

#define GQ0(SB, MT) { \
    ga0 = *(const f16x8*)&Xs[SB][(MT) * 16 + c][hk * 8]; \
    ga1 = *(const f16x8*)&Xs[SB][(MT) * 16 + c][32 + hk * 8]; \
    G0 = MFMA16(ga0, g00h, Z4); G0 = MFMA16(ga1, g01h, G0); \
    H0 = MFMA16(ga0, g00l, Z4); H0 = MFMA16(ga1, g01l, H0); }
#define GQ1() { \
    G1 = MFMA16(ga0, g10h, Z4); G1 = MFMA16(ga1, g11h, G1); \
    H1 = MFMA16(ga0, g10l, Z4); H1 = MFMA16(ga1, g11l, H1); }
#define GQ2() { \
    G2 = MFMA16(ga0, g20h, Z4); G2 = MFMA16(ga1, g21h, G2); \
    H2 = MFMA16(ga0, g20l, Z4); H2 = MFMA16(ga1, g21l, H2); }
#define GQ3(DB, MT) { \
    G3 = MFMA16(ga0, g30h, Z4); G3 = MFMA16(ga1, g31h, G3); \
    H3 = MFMA16(ga0, g30l, Z4); H3 = MFMA16(ga1, g31l, H3); \
    GPK(DB, MT, 0) GPK(DB, MT, 1) GPK(DB, MT, 2) GPK(DB, MT, 3) }

    // prologue: XG[0] from Xs[0] (full, one-time)
    if (!is_scan) {
        GQ0(0, 0) GQ1() GQ2() GQ3(0, 0)
        GQ0(0, 1) GQ1() GQ2() GQ3(0, 1)
        GQ0(0, 2) GQ1() GQ2() GQ3(0, 2)
        GQ0(0, 3) GQ1() GQ2() GQ3(0, 3)
    }
    __syncthreads();

    // scan step: xg folded into MFMA C-in; single-term W_hh; gates lane-local
#define SCAN_STEP(TT, CUR) { \
    const int p = (TT) & 1; \
    const f16x8 ah0 = *(const f16x8*)&Hst[p][0][c][hk * 8]; \
    const f16x8 ah1 = *(const f16x8*)&Hst[p][1][c][hk * 8]; \
    const f32x4 xg4 = *(const f32x4*)&XGb[CUR][TT][hk][16 * w + c][0]; \
    __builtin_amdgcn_s_setprio(1); \
    f32x4 A0 = MFMA16(ah0, s00h, ((f32x4){xg4[0], 0.f, 0.f, 0.f})); \
    A0 = MFMA16(ah1, s01h, A0); \
    f32x4 A1 = MFMA16(ah0, s10h, ((f32x4){xg4[1], 0.f, 0.f, 0.f})); \
    A1 = MFMA16(ah1, s11h, A1); \
    f32x4 A2 = MFMA16(ah0, s20h, ((f32x4){xg4[2], 0.f, 0.f, 0.f})); \
    A2 = MFMA16(ah1, s21h, A2); \
    f32x4 A3 = MFMA16(ah0, s30h, ((f32x4){xg4[3], 0.f, 0.f, 0.f})); \
    A3 = MFMA16(ah1, s31h, A3); \
    __builtin_amdgcn_s_setprio(0); \
    const float gi = sigm(A0[0]), gf = sigm(A1[0]); \
    const float gg = tanh_fast(A2[0]), go = sigm(A3[0]); \
    cst = fmaf(gf, cst, gi * gg); \
    const float hv = go * tanh_fast(cst); \
    const int uo = 16 * w + c; \
    Hst[p ^ 1][uo >> 5][4 * hk][uo & 31] = (_Float16)hv; }

#define XISS(E, CH2) if (v##E) xr##E = xp##E[(size_t)(CH2) * (TC * I_DIM)];
#define XCMT(E, BUF) if (v##E) *((_Float16*)Xs + (BUF) * XSHALF + ld##E) = (_Float16)xr##E;

    // ---- main loop: scan chunk ch; gemm builds chunk ch+1 (quarter/step) ----
    for (int ch = 0; ch < NCH; ++ch) {
        const int cur = ch & 1, nx = cur ^ 1;
        const bool cmp = (ch + 1 < NCH);
        const bool stg = (ch + 2 < NCH);
        float xr0=0,xr1=0,xr2=0,xr3=0,xr4=0,xr5=0,xr6=0,
              xr7=0,xr8=0,xr9=0,xr10=0,xr11=0,xr12=0;

        #pragma unroll
        for (int tt = 0; tt < TC; ++tt) {
            if (is_scan) {
                SCAN_STEP(tt, cur)
            } else {
                if (cmp) {
                    const int mt = tt >> 2, gq = tt & 3;
                    if (gq == 0) { GQ0(nx, mt) }
                    if (gq == 1) { GQ1() }
                    if (gq == 2) { GQ2() }
                    if (gq == 3) { GQ3(nx, mt) }
                }
                if (stg) {
                    if (tt == 0) {
                        XISS(0, ch+2) XISS(1, ch+2) XISS(2, ch+2) XISS(3, ch+2)
                        XISS(4, ch+2) XISS(5, ch+2) XISS(6, ch+2) XISS(7, ch+2)
                        XISS(8, ch+2) XISS(9, ch+2) XISS(10, ch+2) XISS(11, ch+2)
                        XISS(12, ch+2)
                    }
                    if (tt == 6)  { XCMT(0, cur)  XCMT(1, cur) }
                    if (tt == 7)  { XCMT(2, cur)  XCMT(3, cur) }
                    if (tt == 8)  { XCMT(4, cur)  XCMT(5, cur) }
                    if (tt == 9)  { XCMT(6, cur)  XCMT(7, cur) }
                    if (tt == 10) { XCMT(8, cur)  XCMT(9, cur) }
                    if (tt == 11) { XCMT(10, cur) XCMT(11, cur) }
                    if (tt == 12) { XCMT(12, cur) }
                }
            }
            BAR();
        }
    }
#undef SCAN_STEP
#undef GQ0
#undef GQ1
#undef GQ2
#undef GQ3
#undef GPK
#undef XISS
#undef XCMT

    __syncthreads();

    // ---- classifier head; h_last (fp16) in Hst[0], rows 4b ----
    if (u < BB * F1_DIM) {           // 128 threads
        const int b = u >> 5, f = u & 31;
        float acc = b1[f];
        #pragma unroll
        for (int j = 0; j < H_DIM; ++j) {
            const float hj = (float)Hst[0][j >> 5][4 * b][j & 31];
            acc = fmaf(hj, W1[f * H_DIM + j], acc);
        }
        f1buf[b][f] = fmaxf(acc, 0.0f);
    }
    __syncthreads();
    if (u < BB * C_DIM) {            // 8 threads
        const int b = u >> 1, cl = u & 1;
        float acc = b2[cl];
        #pragma unroll
        for (int f = 0; f < F1_DIM; ++f)
            acc = fmaf(f1buf[b][f], W2[cl * F1_DIM + f], acc);
        out[(size_t)(b0 + b) * C_DIM + cl] = acc;
    }
}

extern "C" void kernel_launch(void* const* d_in, const int* in_sizes, int n_in,
                              void* d_out, int out_size, void* d_ws, size_t ws_size,
                              hipStream_t stream) {
    const float* x   = (const float*)d_in[0];
    const float* Wih = (const float*)d_in[1];
    const float* Whh = (const float*)d_in[2];
    const float* bih = (const float*)d_in[3];
    const float* bhh = (const float*)d_in[4];
    const float* W1  = (const float*)d_in[5];
    const float* b1  = (const float*)d_in[6];
    const float* W2  = (const float*)d_in[7];
    const float* b2  = (const float*)d_in[8];
    float* out = (float*)d_out;

    hipLaunchKernelGGL(lstm_mfma, dim3(256), dim3(512), 0, stream,
                       x, Wih, Whh, bih, bhh, W1, b1, W2, b2, out);
}